// Round 1
// baseline (195.012 us; speedup 1.0000x reference)
//
#include <hip/hip_runtime.h>

#define NB 32
#define TMAX 512
#define DDIM 384
#define TOUT (TMAX * 7)   // 3584
#define D4 (DDIM / 4)     // 96 float4 per frame
#define FPB 8             // frames per block in expand kernel

// Kernel 1: per-batch masked cumsum of durations, with all-zero fallback.
// One block per batch, TMAX threads.
__global__ void lr_scan_kernel(const int* __restrict__ ds,
                               const int* __restrict__ ilens,
                               int* __restrict__ cum) {
    __shared__ int s[TMAX];
    const int b = blockIdx.x;
    const int t = threadIdx.x;
    const int len = ilens[b];

    int d = (t < len) ? ds[b * TMAX + t] : 0;
    s[t] = d;
    __syncthreads();

    // Hillis-Steele inclusive scan over 512 elements.
    for (int off = 1; off < TMAX; off <<= 1) {
        int v = (t >= off) ? s[t - off] : 0;
        __syncthreads();
        s[t] += v;
        __syncthreads();
    }

    const int total = s[TMAX - 1];
    __syncthreads();
    if (total == 0) {
        // fallback: d = mask (1 for t < len)
        s[t] = (t < len) ? 1 : 0;
        __syncthreads();
        for (int off = 1; off < TMAX; off <<= 1) {
            int v = (t >= off) ? s[t - off] : 0;
            __syncthreads();
            s[t] += v;
            __syncthreads();
        }
    }
    cum[b * TMAX + t] = s[t];
}

// Kernel 2: expand. Each block = 8 consecutive frames of one batch.
// 256 threads; 8*96 = 768 float4 stores per block (3 per thread), fully
// contiguous in the output, so the dominant write stream is coalesced.
__global__ __launch_bounds__(256) void lr_expand_kernel(
        const float4* __restrict__ xs,
        const int* __restrict__ cum,
        float4* __restrict__ out) {
    __shared__ int s_cum[TMAX];
    __shared__ int s_idx[FPB];

    const int b  = blockIdx.y;
    const int f0 = blockIdx.x * FPB;
    const int t  = threadIdx.x;

    s_cum[t]       = cum[b * TMAX + t];
    s_cum[t + 256] = cum[b * TMAX + t + 256];
    __syncthreads();

    const int total = s_cum[TMAX - 1];

    if (t < FPB) {
        const int f = f0 + t;
        // searchsorted(cum, f, side='right'): first i with cum[i] > f
        int lo = 0, hi = TMAX;
        while (lo < hi) {
            int mid = (lo + hi) >> 1;
            if (s_cum[mid] > f) hi = mid; else lo = mid + 1;
        }
        s_idx[t] = (lo < TMAX) ? lo : (TMAX - 1);
    }
    __syncthreads();

    const int base_out = (b * TOUT + f0) * D4;
    const int base_xs  = b * TMAX * D4;

#pragma unroll
    for (int i = 0; i < 3; ++i) {
        const int l   = i * 256 + t;     // 0..767, contiguous across threads
        const int fl  = l / D4;          // local frame 0..7
        const int col = l - fl * D4;     // 0..95
        float4 v = make_float4(0.f, 0.f, 0.f, 0.f);
        if (f0 + fl < total) {
            v = xs[base_xs + s_idx[fl] * D4 + col];
        }
        out[base_out + l] = v;
    }
}

extern "C" void kernel_launch(void* const* d_in, const int* in_sizes, int n_in,
                              void* d_out, int out_size, void* d_ws, size_t ws_size,
                              hipStream_t stream) {
    const float* xs    = (const float*)d_in[0];
    const int*   ds    = (const int*)d_in[1];
    const int*   ilens = (const int*)d_in[2];
    float*       out   = (float*)d_out;
    int*         cum   = (int*)d_ws;   // B*TMAX ints = 64 KB

    lr_scan_kernel<<<NB, TMAX, 0, stream>>>(ds, ilens, cum);

    dim3 grid(TOUT / FPB, NB);
    lr_expand_kernel<<<grid, 256, 0, stream>>>(
        (const float4*)xs, cum, (float4*)out);
}